// Round 3
// baseline (2004.589 us; speedup 1.0000x reference)
//
#include <hip/hip_runtime.h>
#include <hip/hip_bf16.h>
#include <cstdint>
#include <cstddef>

// Problem constants (fixed by reference setup_inputs)
#define NROWS 32768
#define DDIM  512
#define KCB   8192
#define BM    128
#define BN    256
#define BK    64
#define MARGIN 0.5f

typedef short  short8 __attribute__((ext_vector_type(8)));
typedef float  f32x4  __attribute__((ext_vector_type(4)));

__device__ __forceinline__ float bf16u_to_f(unsigned short u) {
    union { unsigned int i; float f; } c; c.i = ((unsigned int)u) << 16; return c.f;
}
__device__ __forceinline__ unsigned short f_to_bf16u(float f) {
    union { __hip_bfloat16 h; unsigned short u; } c; c.h = __float2bfloat16(f); return c.u;
}

__device__ __forceinline__ void gload_lds16(const void* g, void* l) {
    __builtin_amdgcn_global_load_lds(
        (const __attribute__((address_space(1))) unsigned int*)g,
        (__attribute__((address_space(3))) unsigned int*)l, 16, 0, 0);
}

// ---------------- init: best = +inf keys, avg_psum = 0, sd2 = 0 ----------------
__global__ void k_init(unsigned long long* __restrict__ best, float* __restrict__ avg_psum,
                       float* __restrict__ sd2) {
    int i = blockIdx.x * 256 + threadIdx.x;
    if (i < NROWS) best[i] = 0xFFFFFFFFFFFFFFFFULL;
    if (i < KCB)   avg_psum[i] = 0.f;
    if (i == 0)    sd2[0] = 0.f;
}

// ------------- prep: f32 -> bf16 copy + fp64 row sum-of-squares -------------
__global__ __launch_bounds__(256) void k_prep(const float* __restrict__ src,
                                              __hip_bfloat16* __restrict__ dstb,
                                              float* __restrict__ dstsq) {
    int row = blockIdx.x;
    int t = threadIdx.x;
    const float* r = src + (size_t)row * DDIM;
    float2 v = *(const float2*)(r + t * 2);
    double s = (double)v.x * (double)v.x + (double)v.y * (double)v.y;
    __hip_bfloat162 hv;
    hv.x = __float2bfloat16(v.x);
    hv.y = __float2bfloat16(v.y);
    *(__hip_bfloat162*)(dstb + (size_t)row * DDIM + t * 2) = hv;
    __shared__ double red[256];
    red[t] = s; __syncthreads();
    for (int off = 128; off > 0; off >>= 1) {
        if (t < off) red[t] += red[t + off];
        __syncthreads();
    }
    if (t == 0) dstsq[row] = (float)red[0];
}

// ---------------- fused logit GEMM, 3 modes ----------------
// MODE 0: row softmax stats + store bf16 logits (path A pass)
// MODE 1: row softmax stats only               (path B pass 1)
// MODE 2: recompute logits, column exp-sums + candidate fp64 rescore (path B pass 2)
// grid = NROWS/BM blocks, 512 threads (8 waves, 2x4 of 64x64 wave tiles)
template<int MODE>
__global__ __launch_bounds__(512) void k_gemm(
    const __hip_bfloat16* __restrict__ xb, const __hip_bfloat16* __restrict__ cbb,
    const float* __restrict__ b2, __hip_bfloat16* __restrict__ Lb,
    float* __restrict__ snf, float* __restrict__ thrf, float* __restrict__ se,
    const float* __restrict__ x, const float* __restrict__ cb,
    const float* __restrict__ a2, unsigned long long* __restrict__ best,
    float* __restrict__ avg_psum) {
    __shared__ char lds[98304];   // A: 2x16KB, B: 2x32KB (MODE<=1 reuses as 96KB merge buf)
    const int tid  = threadIdx.x;
    const int w    = tid >> 6;
    const int lane = tid & 63;
    const int wr   = w >> 2;      // 0..1
    const int wc   = w & 3;       // 0..3
    const int l15  = lane & 15;
    const int g    = lane >> 4;   // 0..3
    const int row0 = blockIdx.x * BM;

    f32x4 acc[4][4];
    float m_[16], Z_[16], S_[16];
    float sn_r[16], th_r[16];
    if constexpr (MODE <= 1) {
#pragma unroll
        for (int s = 0; s < 16; ++s) { m_[s] = -3.0e38f; Z_[s] = 0.f; S_[s] = 0.f; }
    } else {
#pragma unroll
        for (int mf = 0; mf < 4; ++mf)
#pragma unroll
            for (int i = 0; i < 4; ++i) {
                int n = row0 + wr * 64 + mf * 16 + g * 4 + i;
                sn_r[mf * 4 + i] = snf[n];
                th_r[mf * 4 + i] = thrf[n];
            }
    }
#pragma unroll
    for (int a = 0; a < 4; ++a)
#pragma unroll
        for (int b = 0; b < 4; ++b) acc[a][b] = (f32x4){0.f, 0.f, 0.f, 0.f};

    auto STAGE = [&](int sbuf, int sct, int sks) {
        char* Adst = lds + sbuf * 16384;            // runtime offsets: no
        char* Bdst = lds + 32768 + sbuf * 32768;    // LDS-pointer arrays!
        // A tile: 128 rows x 64 k (16 KB), linear LDS dest, pre-swizzled source
#pragma unroll
        for (int rd = 0; rd < 2; ++rd) {
            int o  = rd * 8192 + tid * 16;
            int r  = o >> 7;                 // 0..127
            int jp = (o >> 4) & 7;
            int jl = jp ^ (r & 7);
            const __hip_bfloat16* srcp = xb + (size_t)(row0 + r) * DDIM + sks * 64 + jl * 8;
            gload_lds16(srcp, Adst + o);
        }
        // B tile: 256 codebook rows x 64 k (32 KB)
#pragma unroll
        for (int rd = 0; rd < 4; ++rd) {
            int o  = rd * 8192 + tid * 16;
            int r  = o >> 7;                 // 0..255
            int jp = (o >> 4) & 7;
            int jl = jp ^ (r & 7);
            const __hip_bfloat16* srcp = cbb + (size_t)(sct * BN + r) * DDIM + sks * 64 + jl * 8;
            gload_lds16(srcp, Bdst + o);
        }
    };

    STAGE(0, 0, 0);
    __syncthreads();
    int buf = 0;

    for (int ct = 0; ct < KCB / BN; ++ct) {       // 32
        for (int ks = 0; ks < DDIM / BK; ++ks) {  // 8
            int tnext = ct * 8 + ks + 1;
            if (tnext < (KCB / BN) * (DDIM / BK)) STAGE(buf ^ 1, tnext >> 3, tnext & 7);
            const char* Asrc = lds + buf * 16384;
            const char* Bsrc = lds + 32768 + buf * 32768;
#pragma unroll
            for (int mk = 0; mk < 2; ++mk) {
                short8 af[4], bfr[4];
                int j0 = mk * 4 + g;
#pragma unroll
                for (int mf = 0; mf < 4; ++mf) {
                    int r  = wr * 64 + mf * 16 + l15;
                    int jp = j0 ^ (r & 7);
                    af[mf] = *(const short8*)(Asrc + r * 128 + jp * 16);
                }
#pragma unroll
                for (int nf = 0; nf < 4; ++nf) {
                    int r  = wc * 64 + nf * 16 + l15;
                    int jp = j0 ^ (r & 7);
                    bfr[nf] = *(const short8*)(Bsrc + r * 128 + jp * 16);
                }
#pragma unroll
                for (int mf = 0; mf < 4; ++mf)
#pragma unroll
                    for (int nf = 0; nf < 4; ++nf)
                        acc[mf][nf] = __builtin_amdgcn_mfma_f32_16x16x32_bf16(
                            af[mf], bfr[nf], acc[mf][nf], 0, 0, 0);
            }
            __syncthreads();
            buf ^= 1;
        }

        // ---- epilogue for this 256-column tile ----
        int cbase = ct * BN + wc * 64;
        float b2v[4];
#pragma unroll
        for (int nf = 0; nf < 4; ++nf) b2v[nf] = b2[cbase + nf * 16 + l15];

        if constexpr (MODE <= 1) {
#pragma unroll
            for (int mf = 0; mf < 4; ++mf) {
                float lv[4][4];  // [nf][i]
#pragma unroll
                for (int nf = 0; nf < 4; ++nf) {
#pragma unroll
                    for (int i = 0; i < 4; ++i) lv[nf][i] = 2.0f * acc[mf][nf][i] - b2v[nf];
                    if constexpr (MODE == 0) {
                        unsigned int p0 = ((unsigned int)f_to_bf16u(lv[nf][1]) << 16) | f_to_bf16u(lv[nf][0]);
                        unsigned int p1 = ((unsigned int)f_to_bf16u(lv[nf][3]) << 16) | f_to_bf16u(lv[nf][2]);
                        size_t c  = (size_t)(cbase + nf * 16 + l15);
                        size_t n0 = (size_t)(row0 + wr * 64 + mf * 16 + g * 4);
                        uint2 pk; pk.x = p0; pk.y = p1;
                        *(uint2*)((char*)Lb + (c * (size_t)NROWS + n0) * 2) = pk;
                    }
                }
#pragma unroll
                for (int i = 0; i < 4; ++i) {
                    int s = mf * 4 + i;
                    float v0 = lv[0][i], v1 = lv[1][i], v2 = lv[2][i], v3 = lv[3][i];
                    float tm = fmaxf(fmaxf(v0, v1), fmaxf(v2, v3));
                    float nm = fmaxf(m_[s], tm);
                    float sc = __expf(m_[s] - nm);
                    float e0 = __expf(v0 - nm), e1 = __expf(v1 - nm);
                    float e2 = __expf(v2 - nm), e3 = __expf(v3 - nm);
                    Z_[s] = Z_[s] * sc + (e0 + e1 + e2 + e3);
                    S_[s] = S_[s] * sc + (v0 * e0 + v1 * e1 + v2 * e2 + v3 * e3);
                    m_[s] = nm;
                }
#pragma unroll
                for (int nf = 0; nf < 4; ++nf) acc[mf][nf] = (f32x4){0.f, 0.f, 0.f, 0.f};
            }
        } else {
            // MODE 2: column exp-sums + candidate detection/rescore
#pragma unroll
            for (int nf = 0; nf < 4; ++nf) {
                int c = cbase + nf * 16 + l15;
                float colp = 0.f;
#pragma unroll
                for (int mf = 0; mf < 4; ++mf) {
#pragma unroll
                    for (int i = 0; i < 4; ++i) {
                        int s = mf * 4 + i;
                        float l = 2.0f * acc[mf][nf][i] - b2v[nf];
                        colp += __expf(l - sn_r[s]);
                        if (l >= th_r[s]) {
                            int n = row0 + wr * 64 + mf * 16 + g * 4 + i;
                            const float* xr  = x  + (size_t)n * DDIM;
                            const float* cr2 = cb + (size_t)c * DDIM;
                            double p = 0.0;
#pragma unroll 4
                            for (int d = 0; d < DDIM; d += 4) {
                                float4 xv = *(const float4*)(xr + d);
                                float4 cv = *(const float4*)(cr2 + d);
                                p = fma((double)xv.x, (double)cv.x, p);
                                p = fma((double)xv.y, (double)cv.y, p);
                                p = fma((double)xv.z, (double)cv.z, p);
                                p = fma((double)xv.w, (double)cv.w, p);
                            }
                            float abf = (float)p;
                            float dd = (a2[n] - 2.0f * abf) + b2v[nf];
                            union { float f; unsigned int u; } cvu; cvu.f = dd;
                            unsigned long long key =
                                ((unsigned long long)cvu.u << 32) | (unsigned int)c;
                            atomicMin(best + n, key);
                        }
                    }
                }
                colp += __shfl_xor(colp, 16);
                colp += __shfl_xor(colp, 32);
                if (g == 0) atomicAdd(avg_psum + c, colp);
#pragma unroll
                for (int mf = 0; mf < 4; ++mf) acc[mf][nf] = (f32x4){0.f, 0.f, 0.f, 0.f};
            }
        }
    }

    if constexpr (MODE <= 1) {
        // ---- final cross-lane / cross-wave merge of row stats via LDS ----
        __syncthreads();
        float* mrg = (float*)lds;   // [128][64][3] = 96 KB exactly
#pragma unroll
        for (int mf = 0; mf < 4; ++mf)
#pragma unroll
            for (int i = 0; i < 4; ++i) {
                int s  = mf * 4 + i;
                int rl = wr * 64 + mf * 16 + g * 4 + i;
                int idx = (rl * 64 + wc * 16 + l15) * 3;
                mrg[idx] = m_[s]; mrg[idx + 1] = Z_[s]; mrg[idx + 2] = S_[s];
            }
        __syncthreads();
        if (tid < BM) {
            int rl = tid;
            float mm = -3.0e38f;
            for (int j = 0; j < 64; ++j) mm = fmaxf(mm, mrg[(rl * 64 + j) * 3]);
            float Zt = 0.f, St = 0.f;
            for (int j = 0; j < 64; ++j) {
                float sc = __expf(mrg[(rl * 64 + j) * 3] - mm);
                Zt += mrg[(rl * 64 + j) * 3 + 1] * sc;
                St += mrg[(rl * 64 + j) * 3 + 2] * sc;
            }
            float sn = mm + __logf(Zt);
            int n = row0 + rl;
            se[n]   = sn - St / Zt;
            snf[n]  = sn;
            thrf[n] = mm - MARGIN;
        }
    }
}

// --------- column pass (path A): avg_probs column sums + fp64 argmin rescore ---------
__global__ __launch_bounds__(256) void k_col(const __hip_bfloat16* __restrict__ Lb,
                                             const float* __restrict__ snf,
                                             const float* __restrict__ thrf,
                                             const float* __restrict__ x,
                                             const float* __restrict__ cb,
                                             const float* __restrict__ a2,
                                             const float* __restrict__ b2,
                                             unsigned long long* __restrict__ best,
                                             float* __restrict__ avg_psum) {
    int c = blockIdx.x;
    int t = threadIdx.x;
    int lane = t & 63;
    const unsigned short* col = (const unsigned short*)Lb + (size_t)c * NROWS;
    float b2v = b2[c];
    const float* cr = cb + (size_t)c * DDIM;
    float accp = 0.f;

    for (int base = 0; base < NROWS; base += 1024) {
        int n0 = base + t * 4;
        ushort4 lv4 = *(const ushort4*)(col + n0);
        float4  sn4 = *(const float4*)(snf + n0);
        float4  th4 = *(const float4*)(thrf + n0);
        unsigned short lu[4] = { lv4.x, lv4.y, lv4.z, lv4.w };
        float sv[4] = { sn4.x, sn4.y, sn4.z, sn4.w };
        float tv[4] = { th4.x, th4.y, th4.z, th4.w };
#pragma unroll
        for (int j = 0; j < 4; ++j) {
            float l = bf16u_to_f(lu[j]);
            accp += __expf(l - sv[j]);
            unsigned long long mk = __ballot(l >= tv[j]);
            while (mk) {
                int src = __ffsll((unsigned long long)mk) - 1;
                mk &= mk - 1;
                int hn = __shfl(n0 + j, src);
                const float* xr = x + (size_t)hn * DDIM;
                float4 xa  = *(const float4*)(xr + lane * 8);
                float4 xb4 = *(const float4*)(xr + lane * 8 + 4);
                float4 ca  = *(const float4*)(cr + lane * 8);
                float4 cb4 = *(const float4*)(cr + lane * 8 + 4);
                double p = 0.0;
                p = fma((double)xa.x,  (double)ca.x,  p);
                p = fma((double)xa.y,  (double)ca.y,  p);
                p = fma((double)xa.z,  (double)ca.z,  p);
                p = fma((double)xa.w,  (double)ca.w,  p);
                p = fma((double)xb4.x, (double)cb4.x, p);
                p = fma((double)xb4.y, (double)cb4.y, p);
                p = fma((double)xb4.z, (double)cb4.z, p);
                p = fma((double)xb4.w, (double)cb4.w, p);
#pragma unroll
                for (int o = 32; o > 0; o >>= 1) p += __shfl_xor(p, o);
                if (lane == 0) {
                    float abf = (float)p;
                    float dd = (a2[hn] - 2.0f * abf) + b2v;   // ref rounding chain
                    union { float f; unsigned int u; } cvu; cvu.f = dd;
                    unsigned long long key = ((unsigned long long)cvu.u << 32) | (unsigned int)c;
                    atomicMin(best + hn, key);
                }
            }
        }
    }
    __shared__ float red[256];
    red[t] = accp; __syncthreads();
    for (int off = 128; off > 0; off >>= 1) {
        if (t < off) red[t] += red[t + off];
        __syncthreads();
    }
    if (t == 0) avg_psum[c] = red[0];
}

// --------- gather: quantized_ste, indices, sum of squared diffs ---------
__global__ __launch_bounds__(256) void k_gather(const float* __restrict__ x,
                                                const float* __restrict__ cb,
                                                const unsigned long long* __restrict__ best,
                                                float* __restrict__ outq,
                                                float* __restrict__ outidx,
                                                float* __restrict__ sd2) {
    int t  = threadIdx.x;
    int rb = blockIdx.x;
    float acc = 0.f;
    for (int r = 0; r < 128; ++r) {
        int n = rb * 128 + r;
        int idx = (int)(best[n] & 0xFFFFFFFFULL);
        if (idx > KCB - 1 || idx < 0) idx = 0;   // safety (should never trigger)
        const float* xr  = x  + (size_t)n * DDIM;
        const float* crp = cb + (size_t)idx * DDIM;
        float2 xv = *(const float2*)(xr + t * 2);
        float2 qv = *(const float2*)(crp + t * 2);
        float d0 = qv.x - xv.x, d1 = qv.y - xv.y;
        float2 ov; ov.x = xv.x + d0; ov.y = xv.y + d1;   // x + (q - x), reference STE rounding
        *(float2*)(outq + (size_t)n * DDIM + t * 2) = ov;
        acc += d0 * d0 + d1 * d1;
    }
    if (t < 128) {
        int n = rb * 128 + t;
        int idx = (int)(best[n] & 0xFFFFFFFFULL);
        if (idx > KCB - 1 || idx < 0) idx = 0;
        outidx[n] = (float)idx;
    }
    __shared__ float red[256];
    red[t] = acc; __syncthreads();
    for (int off = 128; off > 0; off >>= 1) {
        if (t < off) red[t] += red[t + off];
        __syncthreads();
    }
    if (t == 0) atomicAdd(sd2, red[0]);
}

// ------------------------- final scalars -------------------------
__global__ __launch_bounds__(256) void k_final(const float* __restrict__ se,
                                               const float* __restrict__ avg_psum,
                                               const float* __restrict__ sd2,
                                               float* __restrict__ outsc) {
    int t = threadIdx.x;
    float ses = 0.f;
    for (int n = t; n < NROWS; n += 256) ses += se[n];
    float aes = 0.f;
    const float invN = 1.0f / (float)NROWS;
    for (int c = t; c < KCB; c += 256) {
        float ap = avg_psum[c] * invN;
        aes += ap * __logf(ap + 1e-5f);
    }
    __shared__ float r1[256], r2[256];
    r1[t] = ses; r2[t] = aes; __syncthreads();
    for (int off = 128; off > 0; off >>= 1) {
        if (t < off) { r1[t] += r1[t + off]; r2[t] += r2[t + off]; }
        __syncthreads();
    }
    if (t == 0) {
        float sample_entropy = r1[0] * invN;
        float avg_entropy = -r2[0];
        float mse = sd2[0] / (float)((size_t)NROWS * DDIM);
        float e = 0.25f * mse;
        float q = 1.0f * mse;
        float ent = 0.1f * (sample_entropy - avg_entropy);
        outsc[0] = e + q + ent;   // loss
        outsc[1] = e;             // e_latent_loss
        outsc[2] = q;             // q_latent_loss
        outsc[3] = ent;           // entropy_loss
    }
}

extern "C" void kernel_launch(void* const* d_in, const int* in_sizes, int n_in,
                              void* d_out, int out_size, void* d_ws, size_t ws_size,
                              hipStream_t stream) {
    (void)in_sizes; (void)n_in; (void)out_size;
    const float* x  = (const float*)d_in[0];
    const float* cb = (const float*)d_in[1];
    float* out = (float*)d_out;

    char* ws = (char*)d_ws;
    size_t off = 0;
    auto alloc = [&](size_t bytes) -> char* {
        char* p = ws + off;
        off += (bytes + 255) & ~(size_t)255;
        return p;
    };
    // small arrays first so path B never touches the Lb region
    float* a2  = (float*)alloc((size_t)NROWS * 4);
    float* b2  = (float*)alloc((size_t)KCB * 4);
    float* snf = (float*)alloc((size_t)NROWS * 4);
    float* thrf= (float*)alloc((size_t)NROWS * 4);
    float* se  = (float*)alloc((size_t)NROWS * 4);
    unsigned long long* best = (unsigned long long*)alloc((size_t)NROWS * 8);
    float* avg_psum = (float*)alloc((size_t)KCB * 4);
    float* sd2 = (float*)alloc(256);
    __hip_bfloat16* xb  = (__hip_bfloat16*)alloc((size_t)NROWS * DDIM * 2);
    __hip_bfloat16* cbb = (__hip_bfloat16*)alloc((size_t)KCB * DDIM * 2);
    __hip_bfloat16* Lb  = (__hip_bfloat16*)alloc((size_t)NROWS * KCB * 2);
    bool pathA = (off <= ws_size);

    k_init<<<NROWS / 256, 256, 0, stream>>>(best, avg_psum, sd2);
    k_prep<<<NROWS, 256, 0, stream>>>(x, xb, a2);
    k_prep<<<KCB, 256, 0, stream>>>(cb, cbb, b2);
    if (pathA) {
        k_gemm<0><<<NROWS / BM, 512, 0, stream>>>(xb, cbb, b2, Lb, snf, thrf, se,
                                                  x, cb, a2, best, avg_psum);
        k_col<<<KCB, 256, 0, stream>>>(Lb, snf, thrf, x, cb, a2, b2, best, avg_psum);
    } else {
        k_gemm<1><<<NROWS / BM, 512, 0, stream>>>(xb, cbb, b2, nullptr, snf, thrf, se,
                                                  x, cb, a2, best, avg_psum);
        k_gemm<2><<<NROWS / BM, 512, 0, stream>>>(xb, cbb, b2, nullptr, snf, thrf, se,
                                                  x, cb, a2, best, avg_psum);
    }
    k_gather<<<NROWS / 128, 256, 0, stream>>>(x, cb, best, out,
                                              out + (size_t)NROWS * DDIM, sd2);
    k_final<<<1, 256, 0, stream>>>(se, avg_psum, sd2,
                                   out + (size_t)NROWS * DDIM + NROWS);
}